// Round 12
// baseline (2606.472 us; speedup 1.0000x reference)
//
#include <hip/hip_runtime.h>

// ---------------- problem constants ----------------
#define T_STEPS 128
#define N_B     512
#define D_IN    1024
#define H_DIM   1024
#define G_DIM   3072        // 3*H
#define M_ALL   (T_STEPS * N_B)   // 65536 rows
#define BAR_STRIDE 64       // 256B per barrier counter (kill false sharing across XCDs)

typedef short          s8v  __attribute__((ext_vector_type(8)));   // 8 bf16 (4 VGPR)
typedef float          f4v  __attribute__((ext_vector_type(4)));
typedef unsigned short u4v  __attribute__((ext_vector_type(4)));

__device__ __forceinline__ unsigned short f2bf(float f) {
  union { float f; unsigned u; } v; v.f = f;
  unsigned r = v.u + 0x7FFFu + ((v.u >> 16) & 1u);   // RNE
  return (unsigned short)(r >> 16);
}
__device__ __forceinline__ float bf2f(unsigned short h) {
  union { unsigned u; float f; } v; v.u = ((unsigned)h) << 16;
  return v.f;
}
__device__ __forceinline__ void async16(const void* g, void* l) {
  __builtin_amdgcn_global_load_lds(
      (const __attribute__((address_space(1))) unsigned*)g,
      (__attribute__((address_space(3))) unsigned*)l, 16, 0, 0);
}
// sc0: bypass stale vL1, read fresh from the (XCD-local) L2 — for cross-block h state
__device__ __forceinline__ void async16_sc0(const void* g, void* l) {
  __builtin_amdgcn_global_load_lds(
      (const __attribute__((address_space(1))) unsigned*)g,
      (__attribute__((address_space(3))) unsigned*)l, 16, 0, 1);
}
__device__ __forceinline__ float sigmoidf_(float x) { return 1.f / (1.f + __expf(-x)); }
__device__ __forceinline__ float tanhf_(float x)    { return 1.f - 2.f / (1.f + __expf(2.f * x)); }

// ---------------- f32 -> bf16 conversion (vectorized, grid-stride) ----------------
__global__ void cvt_bf16(const float* __restrict__ in, unsigned short* __restrict__ out, long n4) {
  long i = (long)blockIdx.x * blockDim.x + threadIdx.x;
  long stride = (long)gridDim.x * blockDim.x;
  for (; i < n4; i += stride) {
    f4v v = *(const f4v*)(in + i * 4);
    u4v o;
    #pragma unroll
    for (int e = 0; e < 4; ++e) o[e] = f2bf(v[e]);
    *(u4v*)(out + i * 4) = o;
  }
}

// ---------------- reset[t] = (t==0) || any(m[t,:]==1.0) ----------------
__global__ void reset_kernel(const float* __restrict__ masks, int* __restrict__ reset) {
  const int t = blockIdx.x;
  __shared__ int flag;
  if (threadIdx.x == 0) flag = (t == 0) ? 1 : 0;
  __syncthreads();
  if (t > 0 && masks[(size_t)t * N_B + threadIdx.x] == 1.0f) flag = 1;  // benign same-value race
  __syncthreads();
  if (threadIdx.x == 0) reset[t] = flag;
}

// ---------------- xp GEMM (ALL timesteps), TRANSPOSED output + LDS swizzle ----------------
// C^T[g][m] = sum_k A[m][k]*B[g][k] + bias[g]. Proven R11: 0 bank conflicts, ~537us.
__global__ __launch_bounds__(256) void gemm_xp(const unsigned short* __restrict__ A,
                                               const unsigned short* __restrict__ B,
                                               const float* __restrict__ bias,
                                               unsigned short* __restrict__ C) {
  const int m0 = blockIdx.y * 128, g0 = blockIdx.x * 128;
  const int tid = threadIdx.x, wv = tid >> 6, l = tid & 63;
  const int l15 = l & 15, l4 = l >> 4;
  const int wr = wv >> 1, wc = wv & 1;
  __shared__ unsigned short As[128 * 64], Bs[128 * 64];

  f4v zero4 = {0.f, 0.f, 0.f, 0.f};
  f4v acc[4][4];
  #pragma unroll
  for (int i = 0; i < 4; ++i)
    #pragma unroll
    for (int j = 0; j < 4; ++j) acc[i][j] = zero4;

  const int srow = l >> 3;                       // row within 8-row segment
  const int selem = ((l & 7) ^ srow) * 8;        // pre-swizzled source col (elements)
  const int swz_rd = (l15 & 7) << 4;             // read-side row-XOR

  for (int kt = 0; kt < 1024; kt += 64) {
    #pragma unroll
    for (int cc = 0; cc < 4; ++cc) {
      int s = wv * 4 + cc;
      int row = s * 8 + srow;
      async16(A + (size_t)(m0 + row) * 1024 + kt + selem, &As[s * 512]);
      async16(B + (size_t)(g0 + row) * 1024 + kt + selem, &Bs[s * 512]);
    }
    __syncthreads();
    #pragma unroll
    for (int ks = 0; ks < 2; ++ks) {
      s8v a[4], b[4];
      #pragma unroll
      for (int i = 0; i < 4; ++i) {
        int ra = wr * 64 + i * 16 + l15, rb = wc * 64 + i * 16 + l15;
        int cb = (ks * 64 + l4 * 16) ^ swz_rd;
        a[i] = *(const s8v*)((const char*)As + ra * 128 + cb);
        b[i] = *(const s8v*)((const char*)Bs + rb * 128 + cb);
      }
      #pragma unroll
      for (int i = 0; i < 4; ++i)
        #pragma unroll
        for (int j = 0; j < 4; ++j)
          acc[i][j] = __builtin_amdgcn_mfma_f32_16x16x32_bf16(a[i], b[j], acc[i][j], 0, 0, 0);
    }
    __syncthreads();
  }
  #pragma unroll
  for (int j = 0; j < 4; ++j) {
    int gcol = g0 + wc * 64 + j * 16 + l15;
    float bv = bias[gcol];
    #pragma unroll
    for (int i = 0; i < 4; ++i) {
      int mrow = m0 + wr * 64 + i * 16 + l4 * 4;
      u4v o;
      #pragma unroll
      for (int r = 0; r < 4; ++r) o[r] = f2bf(acc[i][j][r] + bv);
      *(u4v*)(C + (size_t)gcol * M_ALL + mrow) = o;    // transposed, 8B vector store
    }
  }
}

// ---------------- persistent GRU recurrence v6: ALL 128 steps in one launch ----------------
// Composition of proven pieces:
//   - n-major XCD-pure mapping (R6-proven sc0-only coherence): g = bid&7 -> n-group of 64 rows,
//     all 32 blocks of group g on XCD g; h exchange stays in that XCD's L2 (normal stores,
//     vL1 write-through; readers use sc0 loads). c = bid>>3 -> j-chunk of 32 cols.
//   - R11-proven counted-vmcnt kt pipeline (23/13/13/10/10/10/10/0) with XP LDS staging.
//   - hreg (f32 h state) carried in registers across ALL steps (block owns its (n,j) slice).
//   - NEW FIX: barrier counters padded to 256B each — R4/R6/R9 had all 8 groups' counters in
//     one cache line, so "XCD-local" barriers actually bounced a single line device-wide.
__global__ __launch_bounds__(256) void rnn_chunk6(
    const unsigned short* __restrict__ Whh,   // [3072][1024] bf16
    const unsigned short* __restrict__ xpT,   // [3072][65536] bf16 (+b_ih), transposed
    const float* __restrict__ masks,          // [T*N]
    const int* __restrict__ reset,            // [T]
    const float* __restrict__ bhh,            // [3072]
    const float* __restrict__ hxs,            // [512][1024] initial h (f32)
    unsigned short* hbuf,                     // [2][512][1024] bf16 state
    float* __restrict__ y,                    // [T*N][1024] (d_out)
    float* __restrict__ hlast,                // [512][1024]  (d_out tail)
    unsigned* bar) {                          // [8*BAR_STRIDE] padded group counters
  const int bid = blockIdx.x;
  const int g = bid & 7, c = bid >> 3;
  const int n0 = g * 64, j0 = c * 32;
  const int tid = threadIdx.x, w = tid >> 6, l = tid & 63;
  const int l15 = l & 15, l4 = l >> 4;
  const int wn = w & 1, wj = w >> 1;          // wave -> (n-half of 32, j-half of 16)
  const size_t NH = (size_t)N_B * H_DIM;

  __shared__ unsigned short Hs[3][64 * 128];  // 48 KB (h slab, swizzled)
  __shared__ unsigned short Ws[3][96 * 128];  // 72 KB (W slab, swizzled)
  __shared__ unsigned short xpl[3][32][64];   // 12 KB xp gate operands (swizzled cols)

  const int lrow4 = l >> 4;                   // staging: lane -> row-within-4
  const int lcb = (l & 15) * 16;              // staging: lane -> 16B col slot
  const int swz_rd = (l15 & 7) << 4;          // read-side row-XOR

  const int jj = j0 + wj * 16 + l15;
  const float br = bhh[jj];
  const float bz = bhh[H_DIM + jj];
  const float bn = bhh[2 * H_DIM + jj];

  // h state f32 in registers for ALL steps: (i,r) -> n = n0+wn*32+i*16+l4*4+r, col jj
  float hreg[2][4];
  #pragma unroll
  for (int i = 0; i < 2; ++i)
    #pragma unroll
    for (int r = 0; r < 4; ++r)
      hreg[i][r] = hxs[(size_t)(n0 + wn * 32 + i * 16 + l4 * 4 + r) * H_DIM + jj];

  f4v zero4 = {0.f, 0.f, 0.f, 0.f};
  s8v zer8 = {0, 0, 0, 0, 0, 0, 0, 0};

  for (int t = 0; t < T_STEPS; ++t) {
    const unsigned short* hread = hbuf + (size_t)(t & 1) * NH;
    unsigned short* hwrite = hbuf + (size_t)((t & 1) ^ 1) * NH;
    const int rst = reset[t];

    // ---- P: mask loads first (10 VMEM; oldest, absorbed by kt0's wait) ----
    bool zo[2];
    #pragma unroll
    for (int i = 0; i < 2; ++i) {
      float mv = masks[(size_t)t * N_B + n0 + wn * 32 + i * 16 + l15];
      zo[i] = rst && (mv == 0.0f);
    }
    float mreg[2][4];
    #pragma unroll
    for (int i = 0; i < 2; ++i)
      #pragma unroll
      for (int r = 0; r < 4; ++r)
        mreg[i][r] = masks[(size_t)t * N_B + n0 + wn * 32 + i * 16 + l4 * 4 + r];

    f4v acc[2][3];
    #pragma unroll
    for (int i = 0; i < 2; ++i)
      #pragma unroll
      for (int g3 = 0; g3 < 3; ++g3) acc[i][g3] = zero4;

    // ---- staging: 10 builtin VMEM per call; h via sc0 (fresh from XCD-local L2) ----
    auto stage = [&](int buf, int kt) {
      #pragma unroll
      for (int q = 0; q < 4; ++q) {
        int rb = w * 16 + q * 4;
        int row = rb + lrow4;                                   // 0..63
        int cb = lcb ^ ((row & 7) << 4);                        // byte in 256B row
        async16_sc0(hread + (size_t)(n0 + row) * H_DIM + kt * 128 + (cb >> 1),
                    &Hs[buf][rb * 128]);
      }
      #pragma unroll
      for (int q = 0; q < 6; ++q) {
        int rb = w * 24 + q * 4;
        int row = rb + lrow4;                                   // 0..95
        int gate = row >> 5, jjl = row & 31;
        int cb = lcb ^ ((row & 7) << 4);
        async16(Whh + ((size_t)gate * H_DIM + j0 + jjl) * H_DIM + kt * 128 + (cb >> 1),
                &Ws[buf][rb * 128]);
      }
    };

    stage(0, 0); stage(1, 1); stage(2, 2);     // 30 VMEM: three slabs prestaged

    // ---- XP: xp^T gate operands -> LDS (3 builtin VMEM/wave; lands by kt3) ----
    {
      const int jl = w * 8 + (l >> 3);
      const int nelem = ((l & 7) ^ (l >> 3)) * 8;               // pre-swizzled n-offset
      #pragma unroll
      for (int g3 = 0; g3 < 3; ++g3)
        async16(xpT + (size_t)(g3 * H_DIM + j0 + jl) * M_ALL + (size_t)t * N_B + n0 + nelem,
                &xpl[g3][w * 8][0]);
    }

    // ---- kt pipeline: exact counted vmcnt + raw s_barrier (R11-proven) ----
#define KT_BODY(KT, VM, DO_STAGE)                                              \
    {                                                                          \
      asm volatile("s_waitcnt vmcnt(" #VM ")" ::: "memory");                   \
      __builtin_amdgcn_s_barrier();                                            \
      __builtin_amdgcn_sched_barrier(0);                                       \
      if (DO_STAGE) stage((KT + 2) % 3, KT + 2);                               \
      const char* hb = (const char*)&Hs[KT % 3][0];                            \
      const char* wb = (const char*)&Ws[KT % 3][0];                            \
      _Pragma("unroll")                                                        \
      for (int ks = 0; ks < 4; ++ks) {                                         \
        const int kbb = (ks * 64 + l4 * 16) ^ swz_rd;                          \
        s8v a[2], b[3];                                                        \
        _Pragma("unroll")                                                      \
        for (int i = 0; i < 2; ++i) {                                          \
          a[i] = *(const s8v*)(hb + (wn * 32 + i * 16 + l15) * 256 + kbb);     \
          if (zo[i]) a[i] = zer8;                                              \
        }                                                                      \
        _Pragma("unroll")                                                      \
        for (int g3 = 0; g3 < 3; ++g3)                                         \
          b[g3] = *(const s8v*)(wb + (g3 * 32 + wj * 16 + l15) * 256 + kbb);   \
        _Pragma("unroll")                                                      \
        for (int i = 0; i < 2; ++i)                                            \
          _Pragma("unroll")                                                    \
          for (int g3 = 0; g3 < 3; ++g3)                                       \
            acc[i][g3] = __builtin_amdgcn_mfma_f32_16x16x32_bf16(a[i], b[g3],  \
                                                                acc[i][g3], 0, 0, 0); \
      }                                                                        \
    }

    KT_BODY(0, 23, false)
    KT_BODY(1, 13, true)
    KT_BODY(2, 13, true)
    KT_BODY(3, 10, true)
    KT_BODY(4, 10, true)
    KT_BODY(5, 10, true)
    KT_BODY(6, 10, false)
    KT_BODY(7, 0,  false)
#undef KT_BODY

    // ---- gates: xp from LDS, h_prev from registers ----
    #pragma unroll
    for (int i = 0; i < 2; ++i) {
      #pragma unroll
      for (int r = 0; r < 4; ++r) {
        const int n = n0 + wn * 32 + i * 16 + l4 * 4 + r;
        const int nl = wn * 32 + i * 16 + l4 * 4 + r;           // n-local 0..63
        const int jl = wj * 16 + l15;                           // j-local 0..31
        float hprev = hreg[i][r];
        if (rst && mreg[i][r] == 0.0f) hprev = 0.0f;
        const float hr = acc[i][0][r] + br;
        const float hz = acc[i][1][r] + bz;
        const float hn = acc[i][2][r] + bn;
        const char* xb = (const char*)&xpl[0][0][0];
        const int nb = (nl * 2) ^ ((jl & 7) << 4);              // swizzled byte in 128B col
        const float xr = bf2f(*(const unsigned short*)(xb + 0 * 4096 + jl * 128 + nb));
        const float xz = bf2f(*(const unsigned short*)(xb + 1 * 4096 + jl * 128 + nb));
        const float xn = bf2f(*(const unsigned short*)(xb + 2 * 4096 + jl * 128 + nb));
        const float rg = sigmoidf_(xr + hr);
        const float zg = sigmoidf_(xz + hz);
        const float ng = tanhf_(xn + rg * hn);
        const float hnew = (1.f - zg) * ng + zg * hprev;
        hreg[i][r] = hnew;
        const size_t gidx = (size_t)n * H_DIM + jj;
        y[(size_t)t * NH + gidx] = hnew;
        hwrite[gidx] = f2bf(hnew);
        if (t == T_STEPS - 1) hlast[gidx] = hnew;
      }
    }

    // ---- XCD-local group barrier (32 blocks), padded counter, relaxed atomics ----
    __syncthreads();                            // drains vmcnt(0): h stores are in local L2
    if (tid == 0) {
      __hip_atomic_fetch_add(&bar[g * BAR_STRIDE], 1u, __ATOMIC_RELAXED, __HIP_MEMORY_SCOPE_AGENT);
      const unsigned tgt = 32u * (unsigned)(t + 1);
      while (__hip_atomic_load(&bar[g * BAR_STRIDE], __ATOMIC_RELAXED, __HIP_MEMORY_SCOPE_AGENT) < tgt)
        __builtin_amdgcn_s_sleep(1);
    }
    __syncthreads();
  }
}

// ---------------- final LayerNorm over y rows (in place) ----------------
__global__ __launch_bounds__(256) void ln_kernel(float* __restrict__ y,
                                                 const float* __restrict__ gamma,
                                                 const float* __restrict__ beta) {
  const size_t row = blockIdx.x;
  float* p = y + row * (size_t)H_DIM;
  const int tid = threadIdx.x;
  f4v v = *(const f4v*)(p + tid * 4);
  float s = v[0] + v[1] + v[2] + v[3];
  float q = v[0] * v[0] + v[1] * v[1] + v[2] * v[2] + v[3] * v[3];
  #pragma unroll
  for (int off = 32; off > 0; off >>= 1) {
    s += __shfl_down(s, off);
    q += __shfl_down(q, off);
  }
  __shared__ float sb[8];
  const int wid = tid >> 6, lid = tid & 63;
  if (lid == 0) { sb[wid] = s; sb[4 + wid] = q; }
  __syncthreads();
  float S = sb[0] + sb[1] + sb[2] + sb[3];
  float Q = sb[4] + sb[5] + sb[6] + sb[7];
  float mean = S * (1.f / H_DIM);
  float var = Q * (1.f / H_DIM) - mean * mean;
  float inv = rsqrtf(var + 1e-5f);
  f4v g4 = *(const f4v*)(gamma + tid * 4);
  f4v b4 = *(const f4v*)(beta + tid * 4);
  f4v o;
  #pragma unroll
  for (int e = 0; e < 4; ++e) o[e] = (v[e] - mean) * inv * g4[e] + b4[e];
  *(f4v*)(p + tid * 4) = o;
}

// ---------------- host ----------------
extern "C" void kernel_launch(void* const* d_in, const int* in_sizes, int n_in,
                              void* d_out, int out_size, void* d_ws, size_t ws_size,
                              hipStream_t stream) {
  const float* x     = (const float*)d_in[0];
  const float* hxs   = (const float*)d_in[1];
  const float* masks = (const float*)d_in[2];
  const float* W_ih  = (const float*)d_in[3];
  const float* W_hh  = (const float*)d_in[4];
  const float* b_ih  = (const float*)d_in[5];
  const float* b_hh  = (const float*)d_in[6];
  const float* gamma = (const float*)d_in[7];
  const float* beta  = (const float*)d_in[8];
  float* y = (float*)d_out;                                 // [65536][1024]
  float* hlast = y + (size_t)T_STEPS * N_B * H_DIM;         // [512][1024]

  char* ws = (char*)d_ws;
  unsigned short* Wih_bf = (unsigned short*)ws;  ws += (size_t)G_DIM * D_IN * 2;       // 6.3 MB
  unsigned short* Whh_bf = (unsigned short*)ws;  ws += (size_t)G_DIM * H_DIM * 2;      // 6.3 MB
  unsigned short* xc_bf  = (unsigned short*)ws;  ws += (size_t)M_ALL * D_IN * 2;       // 134 MB
  unsigned short* xpT_bf = (unsigned short*)ws;  ws += (size_t)G_DIM * M_ALL * 2;      // 403 MB
  unsigned short* hbuf   = (unsigned short*)ws;  ws += (size_t)2 * N_B * H_DIM * 2;    // 2.1 MB
  unsigned* bars         = (unsigned*)ws;        ws += 8 * BAR_STRIDE * sizeof(unsigned);
  int* reset             = (int*)ws;             ws += 512;

  hipMemsetAsync(bars, 0, 8 * BAR_STRIDE * sizeof(unsigned), stream);
  cvt_bf16<<<1024, 256, 0, stream>>>(W_ih, Wih_bf, (long)G_DIM * D_IN / 4);
  cvt_bf16<<<1024, 256, 0, stream>>>(W_hh, Whh_bf, (long)G_DIM * H_DIM / 4);
  cvt_bf16<<<512, 256, 0, stream>>>(hxs, hbuf, (long)N_B * H_DIM / 4);   // hbuf[0] = bf16(h0)
  reset_kernel<<<128, 512, 0, stream>>>(masks, reset);
  cvt_bf16<<<4096, 256, 0, stream>>>(x, xc_bf, (long)M_ALL * D_IN / 4);

  dim3 gg(G_DIM / 128, M_ALL / 128);   // (24, 512) — one GEMM for all timesteps
  gemm_xp<<<gg, 256, 0, stream>>>(xc_bf, Wih_bf, b_ih, xpT_bf);

  rnn_chunk6<<<256, 256, 0, stream>>>(Whh_bf, xpT_bf, masks, reset, b_hh,
                                      hxs, hbuf, y, hlast, bars);

  ln_kernel<<<T_STEPS * N_B, 256, 0, stream>>>(y, gamma, beta);
}

// Round 13
// 2287.440 us; speedup vs baseline: 1.1395x; 1.1395x over previous
//
#include <hip/hip_runtime.h>

// ---------------- problem constants ----------------
#define T_STEPS 128
#define N_B     512
#define D_IN    1024
#define H_DIM   1024
#define G_DIM   3072        // 3*H
#define M_ALL   (T_STEPS * N_B)   // 65536 rows
#define CHUNK   16
#define NCHUNK  8
#define BAR_STRIDE 64       // 256B per barrier counter (kill false sharing)

typedef short          s8v  __attribute__((ext_vector_type(8)));   // 8 bf16 (4 VGPR)
typedef float          f4v  __attribute__((ext_vector_type(4)));
typedef unsigned short u4v  __attribute__((ext_vector_type(4)));

__device__ __forceinline__ unsigned short f2bf(float f) {
  union { float f; unsigned u; } v; v.f = f;
  unsigned r = v.u + 0x7FFFu + ((v.u >> 16) & 1u);   // RNE
  return (unsigned short)(r >> 16);
}
__device__ __forceinline__ float bf2f(unsigned short h) {
  union { unsigned u; float f; } v; v.u = ((unsigned)h) << 16;
  return v.f;
}
__device__ __forceinline__ void async16(const void* g, void* l) {
  __builtin_amdgcn_global_load_lds(
      (const __attribute__((address_space(1))) unsigned*)g,
      (__attribute__((address_space(3))) unsigned*)l, 16, 0, 0);
}
// sc0|sc1: bypass stale L1/L2, read from the shared Infinity Cache (cross-XCD h)
__device__ __forceinline__ void async16_coh(const void* g, void* l) {
  __builtin_amdgcn_global_load_lds(
      (const __attribute__((address_space(1))) unsigned*)g,
      (__attribute__((address_space(3))) unsigned*)l, 16, 0, 17);
}
// sc0|sc1 coherent bf16 store: write through to the coherence point (cross-XCD h)
__device__ __forceinline__ void store_bf16_coh(unsigned short* p, unsigned short v) {
  unsigned v32 = v;
  asm volatile("global_store_short %0, %1, off sc0 sc1" :: "v"(p), "v"(v32) : "memory");
}
__device__ __forceinline__ float sigmoidf_(float x) { return 1.f / (1.f + __expf(-x)); }
__device__ __forceinline__ float tanhf_(float x)    { return 1.f - 2.f / (1.f + __expf(2.f * x)); }

// ---------------- f32 -> bf16 conversion (vectorized, grid-stride) ----------------
__global__ void cvt_bf16(const float* __restrict__ in, unsigned short* __restrict__ out, long n4) {
  long i = (long)blockIdx.x * blockDim.x + threadIdx.x;
  long stride = (long)gridDim.x * blockDim.x;
  for (; i < n4; i += stride) {
    f4v v = *(const f4v*)(in + i * 4);
    u4v o;
    #pragma unroll
    for (int e = 0; e < 4; ++e) o[e] = f2bf(v[e]);
    *(u4v*)(out + i * 4) = o;
  }
}

// ---------------- reset[t] = (t==0) || any(m[t,:]==1.0) ----------------
__global__ void reset_kernel(const float* __restrict__ masks, int* __restrict__ reset) {
  const int t = blockIdx.x;
  __shared__ int flag;
  if (threadIdx.x == 0) flag = (t == 0) ? 1 : 0;
  __syncthreads();
  if (t > 0 && masks[(size_t)t * N_B + threadIdx.x] == 1.0f) flag = 1;  // benign same-value race
  __syncthreads();
  if (threadIdx.x == 0) reset[t] = flag;
}

// ---------------- xp GEMM (ALL timesteps), TRANSPOSED output + LDS swizzle ----------------
// Proven R11: 0 bank conflicts, ~537us, MfmaUtil 35%.
__global__ __launch_bounds__(256) void gemm_xp(const unsigned short* __restrict__ A,
                                               const unsigned short* __restrict__ B,
                                               const float* __restrict__ bias,
                                               unsigned short* __restrict__ C) {
  const int m0 = blockIdx.y * 128, g0 = blockIdx.x * 128;
  const int tid = threadIdx.x, wv = tid >> 6, l = tid & 63;
  const int l15 = l & 15, l4 = l >> 4;
  const int wr = wv >> 1, wc = wv & 1;
  __shared__ unsigned short As[128 * 64], Bs[128 * 64];

  f4v zero4 = {0.f, 0.f, 0.f, 0.f};
  f4v acc[4][4];
  #pragma unroll
  for (int i = 0; i < 4; ++i)
    #pragma unroll
    for (int j = 0; j < 4; ++j) acc[i][j] = zero4;

  const int srow = l >> 3;
  const int selem = ((l & 7) ^ srow) * 8;        // pre-swizzled source col (elements)
  const int swz_rd = (l15 & 7) << 4;             // read-side row-XOR

  for (int kt = 0; kt < 1024; kt += 64) {
    #pragma unroll
    for (int cc = 0; cc < 4; ++cc) {
      int s = wv * 4 + cc;
      int row = s * 8 + srow;
      async16(A + (size_t)(m0 + row) * 1024 + kt + selem, &As[s * 512]);
      async16(B + (size_t)(g0 + row) * 1024 + kt + selem, &Bs[s * 512]);
    }
    __syncthreads();
    #pragma unroll
    for (int ks = 0; ks < 2; ++ks) {
      s8v a[4], b[4];
      #pragma unroll
      for (int i = 0; i < 4; ++i) {
        int ra = wr * 64 + i * 16 + l15, rb = wc * 64 + i * 16 + l15;
        int cb = (ks * 64 + l4 * 16) ^ swz_rd;
        a[i] = *(const s8v*)((const char*)As + ra * 128 + cb);
        b[i] = *(const s8v*)((const char*)Bs + rb * 128 + cb);
      }
      #pragma unroll
      for (int i = 0; i < 4; ++i)
        #pragma unroll
        for (int j = 0; j < 4; ++j)
          acc[i][j] = __builtin_amdgcn_mfma_f32_16x16x32_bf16(a[i], b[j], acc[i][j], 0, 0, 0);
    }
    __syncthreads();
  }
  #pragma unroll
  for (int j = 0; j < 4; ++j) {
    int gcol = g0 + wc * 64 + j * 16 + l15;
    float bv = bias[gcol];
    #pragma unroll
    for (int i = 0; i < 4; ++i) {
      int mrow = m0 + wr * 64 + i * 16 + l4 * 4;
      u4v o;
      #pragma unroll
      for (int r = 0; r < 4; ++r) o[r] = f2bf(acc[i][j][r] + bv);
      *(u4v*)(C + (size_t)gcol * M_ALL + mrow) = o;    // transposed, 8B vector store
    }
  }
}

// ---------------- persistent GRU recurrence v7: j-major + PADDED barriers ----------------
// Grid 256 (1/CU): jt = bid&31 (j0=jt*32), nt = bid>>5 (n0=nt*64). XCD=jt%8 -> W slice 768KB
// per XCD, L2-RESIDENT across all 16 steps (R9-proven; FETCH 7.4MB/step). h crosses XCDs via
// L3: sc0|sc1 stores + sc0|sc1 staging loads (R8/R9-proven correct).
// NEW (the fix under test): nt-group barrier counters padded to 256B — R9 had all 8 counters
// in ONE cache line, so every arrival/poll bounced a single line across all 256 blocks.
// Pipeline (R11-proven): P-loads -> S0,S1,S2 -> XP; exact counted vmcnt per kt; xp from LDS.
__global__ __launch_bounds__(256) void rnn_chunk7(
    const unsigned short* __restrict__ Whh,   // [3072][1024] bf16
    const unsigned short* __restrict__ xpT,   // [3072][65536] bf16 (+b_ih), transposed
    const float* __restrict__ masks,          // [T*N]
    const int* __restrict__ reset,            // [T]
    const float* __restrict__ bhh,            // [3072]
    const float* __restrict__ hxs,            // [512][1024] initial h (f32)
    unsigned short* hbuf,                     // [2][512][1024] bf16 state
    float* __restrict__ y,                    // [T*N][1024] (d_out)
    float* __restrict__ hlast,                // [512][1024]  (d_out tail)
    unsigned* bar,                            // [8*BAR_STRIDE] padded nt-group counters
    int t0) {
  const int bid = blockIdx.x;
  const int jt = bid & 31, nt = bid >> 5;
  const int j0 = jt * 32, n0 = nt * 64;
  const int tid = threadIdx.x, w = tid >> 6, l = tid & 63;
  const int l15 = l & 15, l4 = l >> 4;
  const int wn = w & 1, wj = w >> 1;          // wave -> (n-half of 32, j-half of 16)
  const size_t NH = (size_t)N_B * H_DIM;

  __shared__ unsigned short Hs[3][64 * 128];  // 48 KB (h slab, swizzled)
  __shared__ unsigned short Ws[3][96 * 128];  // 72 KB (W slab, swizzled)
  __shared__ unsigned short xpl[3][32][64];   // 12 KB xp gate operands (swizzled cols)

  const int lrow4 = l >> 4;                   // staging: lane -> row-within-4
  const int lcb = (l & 15) * 16;              // staging: lane -> 16B col slot
  const int swz_rd = (l15 & 7) << 4;          // read-side row-XOR

  const int jj = j0 + wj * 16 + l15;
  const float br = bhh[jj];
  const float bz = bhh[H_DIM + jj];
  const float bn = bhh[2 * H_DIM + jj];

  // h_prev f32 in registers, carried across the chunk: (i,r) -> n = n0+wn*32+i*16+l4*4+r
  float hreg[2][4];
  {
    const float* hsrc = (t0 == 0) ? hxs : (y + (size_t)(t0 - 1) * NH);
    #pragma unroll
    for (int i = 0; i < 2; ++i)
      #pragma unroll
      for (int r = 0; r < 4; ++r)
        hreg[i][r] = hsrc[(size_t)(n0 + wn * 32 + i * 16 + l4 * 4 + r) * H_DIM + jj];
  }

  f4v zero4 = {0.f, 0.f, 0.f, 0.f};
  s8v zer8 = {0, 0, 0, 0, 0, 0, 0, 0};

  for (int ls = 0; ls < CHUNK; ++ls) {
    const int t = t0 + ls;
    const unsigned short* hread = hbuf + (size_t)(t & 1) * NH;
    unsigned short* hwrite = hbuf + (size_t)((t & 1) ^ 1) * NH;
    const int rst = reset[t];

    // ---- P: mask loads first (10 VMEM; oldest, absorbed by kt0's wait) ----
    bool zo[2];
    #pragma unroll
    for (int i = 0; i < 2; ++i) {
      float mv = masks[(size_t)t * N_B + n0 + wn * 32 + i * 16 + l15];
      zo[i] = rst && (mv == 0.0f);
    }
    float mreg[2][4];
    #pragma unroll
    for (int i = 0; i < 2; ++i)
      #pragma unroll
      for (int r = 0; r < 4; ++r)
        mreg[i][r] = masks[(size_t)t * N_B + n0 + wn * 32 + i * 16 + l4 * 4 + r];

    f4v acc[2][3];
    #pragma unroll
    for (int i = 0; i < 2; ++i)
      #pragma unroll
      for (int g3 = 0; g3 < 3; ++g3) acc[i][g3] = zero4;

    // ---- staging: 10 builtin VMEM per call; h coherent (L3), W normal (L2-hot) ----
    auto stage = [&](int buf, int kt) {
      #pragma unroll
      for (int q = 0; q < 4; ++q) {
        int rb = w * 16 + q * 4;
        int row = rb + lrow4;                                   // 0..63
        int cb = lcb ^ ((row & 7) << 4);                        // byte in 256B row
        async16_coh(hread + (size_t)(n0 + row) * H_DIM + kt * 128 + (cb >> 1),
                    &Hs[buf][rb * 128]);
      }
      #pragma unroll
      for (int q = 0; q < 6; ++q) {
        int rb = w * 24 + q * 4;
        int row = rb + lrow4;                                   // 0..95
        int gate = row >> 5, jjl = row & 31;
        int cb = lcb ^ ((row & 7) << 4);
        async16(Whh + ((size_t)gate * H_DIM + j0 + jjl) * H_DIM + kt * 128 + (cb >> 1),
                &Ws[buf][rb * 128]);
      }
    };

    stage(0, 0); stage(1, 1); stage(2, 2);     // 30 VMEM: three slabs prestaged

    // ---- XP: xp^T gate operands -> LDS (3 builtin VMEM/wave; lands by kt3) ----
    {
      const int jl = w * 8 + (l >> 3);
      const int nelem = ((l & 7) ^ (l >> 3)) * 8;               // pre-swizzled n-offset
      #pragma unroll
      for (int g3 = 0; g3 < 3; ++g3)
        async16(xpT + (size_t)(g3 * H_DIM + j0 + jl) * M_ALL + (size_t)t * N_B + n0 + nelem,
                &xpl[g3][w * 8][0]);
    }

    // ---- kt pipeline: exact counted vmcnt + raw s_barrier (R11-proven) ----
#define KT_BODY(KT, VM, DO_STAGE)                                              \
    {                                                                          \
      asm volatile("s_waitcnt vmcnt(" #VM ")" ::: "memory");                   \
      __builtin_amdgcn_s_barrier();                                            \
      __builtin_amdgcn_sched_barrier(0);                                       \
      if (DO_STAGE) stage((KT + 2) % 3, KT + 2);                               \
      const char* hb = (const char*)&Hs[KT % 3][0];                            \
      const char* wb = (const char*)&Ws[KT % 3][0];                            \
      _Pragma("unroll")                                                        \
      for (int ks = 0; ks < 4; ++ks) {                                         \
        const int kbb = (ks * 64 + l4 * 16) ^ swz_rd;                          \
        s8v a[2], b[3];                                                        \
        _Pragma("unroll")                                                      \
        for (int i = 0; i < 2; ++i) {                                          \
          a[i] = *(const s8v*)(hb + (wn * 32 + i * 16 + l15) * 256 + kbb);     \
          if (zo[i]) a[i] = zer8;                                              \
        }                                                                      \
        _Pragma("unroll")                                                      \
        for (int g3 = 0; g3 < 3; ++g3)                                         \
          b[g3] = *(const s8v*)(wb + (g3 * 32 + wj * 16 + l15) * 256 + kbb);   \
        _Pragma("unroll")                                                      \
        for (int i = 0; i < 2; ++i)                                            \
          _Pragma("unroll")                                                    \
          for (int g3 = 0; g3 < 3; ++g3)                                       \
            acc[i][g3] = __builtin_amdgcn_mfma_f32_16x16x32_bf16(a[i], b[g3],  \
                                                                acc[i][g3], 0, 0, 0); \
      }                                                                        \
    }

    KT_BODY(0, 23, false)
    KT_BODY(1, 13, true)
    KT_BODY(2, 13, true)
    KT_BODY(3, 10, true)
    KT_BODY(4, 10, true)
    KT_BODY(5, 10, true)
    KT_BODY(6, 10, false)
    KT_BODY(7, 0,  false)
#undef KT_BODY

    // ---- gates: xp from LDS, h_prev from registers ----
    #pragma unroll
    for (int i = 0; i < 2; ++i) {
      #pragma unroll
      for (int r = 0; r < 4; ++r) {
        const int n = n0 + wn * 32 + i * 16 + l4 * 4 + r;
        const int nl = wn * 32 + i * 16 + l4 * 4 + r;           // n-local 0..63
        const int jl = wj * 16 + l15;                           // j-local 0..31
        float hprev = hreg[i][r];
        if (rst && mreg[i][r] == 0.0f) hprev = 0.0f;
        const float hr = acc[i][0][r] + br;
        const float hz = acc[i][1][r] + bz;
        const float hn = acc[i][2][r] + bn;
        const char* xb = (const char*)&xpl[0][0][0];
        const int nb = (nl * 2) ^ ((jl & 7) << 4);              // swizzled byte in 128B col
        const float xr = bf2f(*(const unsigned short*)(xb + 0 * 4096 + jl * 128 + nb));
        const float xz = bf2f(*(const unsigned short*)(xb + 1 * 4096 + jl * 128 + nb));
        const float xn = bf2f(*(const unsigned short*)(xb + 2 * 4096 + jl * 128 + nb));
        const float rg = sigmoidf_(xr + hr);
        const float zg = sigmoidf_(xz + hz);
        const float ng = tanhf_(xn + rg * hn);
        const float hnew = (1.f - zg) * ng + zg * hprev;
        hreg[i][r] = hnew;
        const size_t gidx = (size_t)n * H_DIM + jj;
        y[(size_t)t * NH + gidx] = hnew;
        store_bf16_coh(hwrite + gidx, f2bf(hnew));   // through to coherence point
        if (t == T_STEPS - 1) hlast[gidx] = hnew;
      }
    }

    // ---- nt-group barrier (32 blocks, cross-XCD), PADDED counter, relaxed atomics ----
    __syncthreads();                            // drains vmcnt(0): h stores at coherence point
    if (tid == 0) {
      __hip_atomic_fetch_add(&bar[nt * BAR_STRIDE], 1u, __ATOMIC_RELAXED, __HIP_MEMORY_SCOPE_AGENT);
      const unsigned tgt = 32u * (unsigned)(ls + 1);
      while (__hip_atomic_load(&bar[nt * BAR_STRIDE], __ATOMIC_RELAXED, __HIP_MEMORY_SCOPE_AGENT) < tgt)
        __builtin_amdgcn_s_sleep(1);
    }
    __syncthreads();
  }
}

// ---------------- final LayerNorm over y rows (in place) ----------------
__global__ __launch_bounds__(256) void ln_kernel(float* __restrict__ y,
                                                 const float* __restrict__ gamma,
                                                 const float* __restrict__ beta) {
  const size_t row = blockIdx.x;
  float* p = y + row * (size_t)H_DIM;
  const int tid = threadIdx.x;
  f4v v = *(const f4v*)(p + tid * 4);
  float s = v[0] + v[1] + v[2] + v[3];
  float q = v[0] * v[0] + v[1] * v[1] + v[2] * v[2] + v[3] * v[3];
  #pragma unroll
  for (int off = 32; off > 0; off >>= 1) {
    s += __shfl_down(s, off);
    q += __shfl_down(q, off);
  }
  __shared__ float sb[8];
  const int wid = tid >> 6, lid = tid & 63;
  if (lid == 0) { sb[wid] = s; sb[4 + wid] = q; }
  __syncthreads();
  float S = sb[0] + sb[1] + sb[2] + sb[3];
  float Q = sb[4] + sb[5] + sb[6] + sb[7];
  float mean = S * (1.f / H_DIM);
  float var = Q * (1.f / H_DIM) - mean * mean;
  float inv = rsqrtf(var + 1e-5f);
  f4v g4 = *(const f4v*)(gamma + tid * 4);
  f4v b4 = *(const f4v*)(beta + tid * 4);
  f4v o;
  #pragma unroll
  for (int e = 0; e < 4; ++e) o[e] = (v[e] - mean) * inv * g4[e] + b4[e];
  *(f4v*)(p + tid * 4) = o;
}

// ---------------- host ----------------
extern "C" void kernel_launch(void* const* d_in, const int* in_sizes, int n_in,
                              void* d_out, int out_size, void* d_ws, size_t ws_size,
                              hipStream_t stream) {
  const float* x     = (const float*)d_in[0];
  const float* hxs   = (const float*)d_in[1];
  const float* masks = (const float*)d_in[2];
  const float* W_ih  = (const float*)d_in[3];
  const float* W_hh  = (const float*)d_in[4];
  const float* b_ih  = (const float*)d_in[5];
  const float* b_hh  = (const float*)d_in[6];
  const float* gamma = (const float*)d_in[7];
  const float* beta  = (const float*)d_in[8];
  float* y = (float*)d_out;                                 // [65536][1024]
  float* hlast = y + (size_t)T_STEPS * N_B * H_DIM;         // [512][1024]

  char* ws = (char*)d_ws;
  unsigned short* Wih_bf = (unsigned short*)ws;  ws += (size_t)G_DIM * D_IN * 2;       // 6.3 MB
  unsigned short* Whh_bf = (unsigned short*)ws;  ws += (size_t)G_DIM * H_DIM * 2;      // 6.3 MB
  unsigned short* xc_bf  = (unsigned short*)ws;  ws += (size_t)M_ALL * D_IN * 2;       // 134 MB
  unsigned short* xpT_bf = (unsigned short*)ws;  ws += (size_t)G_DIM * M_ALL * 2;      // 403 MB
  unsigned short* hbuf   = (unsigned short*)ws;  ws += (size_t)2 * N_B * H_DIM * 2;    // 2.1 MB
  unsigned* bars         = (unsigned*)ws;        ws += NCHUNK * 8 * BAR_STRIDE * sizeof(unsigned);
  int* reset             = (int*)ws;             ws += 512;

  hipMemsetAsync(bars, 0, NCHUNK * 8 * BAR_STRIDE * sizeof(unsigned), stream);
  cvt_bf16<<<1024, 256, 0, stream>>>(W_ih, Wih_bf, (long)G_DIM * D_IN / 4);
  cvt_bf16<<<1024, 256, 0, stream>>>(W_hh, Whh_bf, (long)G_DIM * H_DIM / 4);
  cvt_bf16<<<512, 256, 0, stream>>>(hxs, hbuf, (long)N_B * H_DIM / 4);   // hbuf[0] = bf16(h0)
  reset_kernel<<<128, 512, 0, stream>>>(masks, reset);
  cvt_bf16<<<4096, 256, 0, stream>>>(x, xc_bf, (long)M_ALL * D_IN / 4);

  dim3 gg(G_DIM / 128, M_ALL / 128);   // (24, 512) — one GEMM for all timesteps
  gemm_xp<<<gg, 256, 0, stream>>>(xc_bf, Wih_bf, b_ih, xpT_bf);

  for (int ck = 0; ck < NCHUNK; ++ck) {
    rnn_chunk7<<<256, 256, 0, stream>>>(Whh_bf, xpT_bf, masks, reset, b_hh, hxs, hbuf,
                                        y, hlast, bars + (size_t)ck * 8 * BAR_STRIDE,
                                        ck * CHUNK);
  }

  ln_kernel<<<T_STEPS * N_B, 256, 0, stream>>>(y, gamma, beta);
}

// Round 14
// 2263.180 us; speedup vs baseline: 1.1517x; 1.0107x over previous
//
#include <hip/hip_runtime.h>

// ---------------- problem constants ----------------
#define T_STEPS 128
#define N_B     512
#define D_IN    1024
#define H_DIM   1024
#define G_DIM   3072        // 3*H
#define M_ALL   (T_STEPS * N_B)   // 65536 rows
#define BAR_STRIDE 64       // 256B per barrier counter

typedef short          s8v  __attribute__((ext_vector_type(8)));   // 8 bf16 (4 VGPR)
typedef float          f4v  __attribute__((ext_vector_type(4)));
typedef unsigned short u4v  __attribute__((ext_vector_type(4)));

__device__ __forceinline__ unsigned short f2bf(float f) {
  union { float f; unsigned u; } v; v.f = f;
  unsigned r = v.u + 0x7FFFu + ((v.u >> 16) & 1u);   // RNE
  return (unsigned short)(r >> 16);
}
__device__ __forceinline__ float bf2f(unsigned short h) {
  union { unsigned u; float f; } v; v.u = ((unsigned)h) << 16;
  return v.f;
}
__device__ __forceinline__ void async16(const void* g, void* l) {
  __builtin_amdgcn_global_load_lds(
      (const __attribute__((address_space(1))) unsigned*)g,
      (__attribute__((address_space(3))) unsigned*)l, 16, 0, 0);
}
// sc0|sc1: bypass stale L1/L2, read from the shared Infinity Cache (cross-XCD h)
__device__ __forceinline__ void async16_coh(const void* g, void* l) {
  __builtin_amdgcn_global_load_lds(
      (const __attribute__((address_space(1))) unsigned*)g,
      (__attribute__((address_space(3))) unsigned*)l, 16, 0, 17);
}
// sc0|sc1 coherent bf16 store: write through to the coherence point (cross-XCD h)
__device__ __forceinline__ void store_bf16_coh(unsigned short* p, unsigned short v) {
  unsigned v32 = v;
  asm volatile("global_store_short %0, %1, off sc0 sc1" :: "v"(p), "v"(v32) : "memory");
}
__device__ __forceinline__ float sigmoidf_(float x) { return 1.f / (1.f + __expf(-x)); }
__device__ __forceinline__ float tanhf_(float x)    { return 1.f - 2.f / (1.f + __expf(2.f * x)); }

// ---------------- f32 -> bf16 conversion (vectorized, grid-stride) ----------------
__global__ void cvt_bf16(const float* __restrict__ in, unsigned short* __restrict__ out, long n4) {
  long i = (long)blockIdx.x * blockDim.x + threadIdx.x;
  long stride = (long)gridDim.x * blockDim.x;
  for (; i < n4; i += stride) {
    f4v v = *(const f4v*)(in + i * 4);
    u4v o;
    #pragma unroll
    for (int e = 0; e < 4; ++e) o[e] = f2bf(v[e]);
    *(u4v*)(out + i * 4) = o;
  }
}

// ---------------- reset[t] = (t==0) || any(m[t,:]==1.0) ----------------
__global__ void reset_kernel(const float* __restrict__ masks, int* __restrict__ reset) {
  const int t = blockIdx.x;
  __shared__ int flag;
  if (threadIdx.x == 0) flag = (t == 0) ? 1 : 0;
  __syncthreads();
  if (t > 0 && masks[(size_t)t * N_B + threadIdx.x] == 1.0f) flag = 1;  // benign same-value race
  __syncthreads();
  if (threadIdx.x == 0) reset[t] = flag;
}

// ---------------- xp GEMM (ALL timesteps), TRANSPOSED output + LDS swizzle ----------------
// Proven R11/R13: 0 bank conflicts, ~537us, MfmaUtil 35%.
__global__ __launch_bounds__(256) void gemm_xp(const unsigned short* __restrict__ A,
                                               const unsigned short* __restrict__ B,
                                               const float* __restrict__ bias,
                                               unsigned short* __restrict__ C) {
  const int m0 = blockIdx.y * 128, g0 = blockIdx.x * 128;
  const int tid = threadIdx.x, wv = tid >> 6, l = tid & 63;
  const int l15 = l & 15, l4 = l >> 4;
  const int wr = wv >> 1, wc = wv & 1;
  __shared__ unsigned short As[128 * 64], Bs[128 * 64];

  f4v zero4 = {0.f, 0.f, 0.f, 0.f};
  f4v acc[4][4];
  #pragma unroll
  for (int i = 0; i < 4; ++i)
    #pragma unroll
    for (int j = 0; j < 4; ++j) acc[i][j] = zero4;

  const int srow = l >> 3;
  const int selem = ((l & 7) ^ srow) * 8;        // pre-swizzled source col (elements)
  const int swz_rd = (l15 & 7) << 4;             // read-side row-XOR

  for (int kt = 0; kt < 1024; kt += 64) {
    #pragma unroll
    for (int cc = 0; cc < 4; ++cc) {
      int s = wv * 4 + cc;
      int row = s * 8 + srow;
      async16(A + (size_t)(m0 + row) * 1024 + kt + selem, &As[s * 512]);
      async16(B + (size_t)(g0 + row) * 1024 + kt + selem, &Bs[s * 512]);
    }
    __syncthreads();
    #pragma unroll
    for (int ks = 0; ks < 2; ++ks) {
      s8v a[4], b[4];
      #pragma unroll
      for (int i = 0; i < 4; ++i) {
        int ra = wr * 64 + i * 16 + l15, rb = wc * 64 + i * 16 + l15;
        int cb = (ks * 64 + l4 * 16) ^ swz_rd;
        a[i] = *(const s8v*)((const char*)As + ra * 128 + cb);
        b[i] = *(const s8v*)((const char*)Bs + rb * 128 + cb);
      }
      #pragma unroll
      for (int i = 0; i < 4; ++i)
        #pragma unroll
        for (int j = 0; j < 4; ++j)
          acc[i][j] = __builtin_amdgcn_mfma_f32_16x16x32_bf16(a[i], b[j], acc[i][j], 0, 0, 0);
    }
    __syncthreads();
  }
  #pragma unroll
  for (int j = 0; j < 4; ++j) {
    int gcol = g0 + wc * 64 + j * 16 + l15;
    float bv = bias[gcol];
    #pragma unroll
    for (int i = 0; i < 4; ++i) {
      int mrow = m0 + wr * 64 + i * 16 + l4 * 4;
      u4v o;
      #pragma unroll
      for (int r = 0; r < 4; ++r) o[r] = f2bf(acc[i][j][r] + bv);
      *(u4v*)(C + (size_t)gcol * M_ALL + mrow) = o;    // transposed, 8B vector store
    }
  }
}

// ---------------- persistent GRU, v8: ALL 128 steps, prestage-split pipeline ----------------
// Grid 256 (1/CU): jt = bid&31 (j0=jt*32), nt = bid>>5 (n0=nt*64). XCD=jt%8 -> W slice 768KB
// per XCD, L2-resident. h crosses XCDs via L3 (sc0|sc1 stores+loads, R8-R13 proven). Padded
// barrier counters (R13 proven). NEW: everything h-INDEPENDENT (W slabs 0-2, xp(t+1), masks,
// reset) is issued BEFORE the group barrier and completes during the barrier wait; the
// post-barrier critical path is ONLY the 12 h-loads. Barrier exit uses a raw s_barrier (no
// vmcnt(0) drain needed: h reads are sc0|sc1 remote fetches). vmcnt per kt re-derived:
// 8,4,10,10,10,10,10,0 (in-loop stages at kt1..5 for slabs 3..7).
__global__ __launch_bounds__(256, 1) void rnn_all(
    const unsigned short* __restrict__ Whh,   // [3072][1024] bf16
    const unsigned short* __restrict__ xpT,   // [3072][65536] bf16 (+b_ih), transposed
    const float* __restrict__ masks,          // [T*N]
    const int* __restrict__ reset,            // [T]
    const float* __restrict__ bhh,            // [3072]
    const float* __restrict__ hxs,            // [512][1024] initial h (f32)
    unsigned short* hbuf,                     // [2][512][1024] bf16 state
    float* __restrict__ y,                    // [T*N][1024] (d_out)
    float* __restrict__ hlast,                // [512][1024]  (d_out tail)
    unsigned* bar) {                          // [8*BAR_STRIDE] padded nt-group counters
  const int bid = blockIdx.x;
  const int jt = bid & 31, nt = bid >> 5;
  const int j0 = jt * 32, n0 = nt * 64;
  const int tid = threadIdx.x, w = tid >> 6, l = tid & 63;
  const int l15 = l & 15, l4 = l >> 4;
  const int wn = w & 1, wj = w >> 1;          // wave -> (n-half of 32, j-half of 16)
  const size_t NH = (size_t)N_B * H_DIM;

  __shared__ unsigned short Hs[3][64 * 128];  // 48 KB (h slab, swizzled)
  __shared__ unsigned short Ws[3][96 * 128];  // 72 KB (W slab, swizzled)
  __shared__ unsigned short xpl[3][32][64];   // 12 KB xp gate operands (swizzled cols)

  const int lrow4 = l >> 4;                   // staging: lane -> row-within-4
  const int lcb = (l & 15) * 16;              // staging: lane -> 16B col slot
  const int swz_rd = (l15 & 7) << 4;          // read-side row-XOR

  const int jj = j0 + wj * 16 + l15;
  const float br = bhh[jj];
  const float bz = bhh[H_DIM + jj];
  const float bn = bhh[2 * H_DIM + jj];

  // h_prev f32 in registers, carried across ALL 128 steps
  float hreg[2][4];
  #pragma unroll
  for (int i = 0; i < 2; ++i)
    #pragma unroll
    for (int r = 0; r < 4; ++r)
      hreg[i][r] = hxs[(size_t)(n0 + wn * 32 + i * 16 + l4 * 4 + r) * H_DIM + jj];

  f4v zero4 = {0.f, 0.f, 0.f, 0.f};
  s8v zer8 = {0, 0, 0, 0, 0, 0, 0, 0};

  // ---- staging helpers (wave-uniform LDS dest, per-lane pre-swizzled global src) ----
  auto stageH = [&](const unsigned short* hread, int buf, int kt) {  // 4 VMEM/wave
    #pragma unroll
    for (int q = 0; q < 4; ++q) {
      int rb = w * 16 + q * 4;
      int row = rb + lrow4;                                   // 0..63
      int cb = lcb ^ ((row & 7) << 4);                        // byte in 256B row
      async16_coh(hread + (size_t)(n0 + row) * H_DIM + kt * 128 + (cb >> 1),
                  &Hs[buf][rb * 128]);
    }
  };
  auto stageW = [&](int buf, int kt) {                        // 6 VMEM/wave
    #pragma unroll
    for (int q = 0; q < 6; ++q) {
      int rb = w * 24 + q * 4;
      int row = rb + lrow4;                                   // 0..95
      int gate = row >> 5, jjl = row & 31;
      int cb = lcb ^ ((row & 7) << 4);
      async16(Whh + ((size_t)gate * H_DIM + j0 + jjl) * H_DIM + kt * 128 + (cb >> 1),
              &Ws[buf][rb * 128]);
    }
  };
  auto stageXP = [&](int t) {                                 // 3 VMEM/wave
    const int jl = w * 8 + (l >> 3);
    const int nelem = ((l & 7) ^ (l >> 3)) * 8;               // pre-swizzled n-offset
    #pragma unroll
    for (int g3 = 0; g3 < 3; ++g3)
      async16(xpT + (size_t)(g3 * H_DIM + j0 + jl) * M_ALL + (size_t)t * N_B + n0 + nelem,
              &xpl[g3][w * 8][0]);
  };

  // ---- priming for t=0: h-independent prestage (no barrier needed before first step) ----
  int rst = reset[0];
  bool zo[2];
  float mreg[2][4];
  #pragma unroll
  for (int i = 0; i < 2; ++i) {
    float mv = masks[(size_t)0 * N_B + n0 + wn * 32 + i * 16 + l15];
    zo[i] = rst && (mv == 0.0f);
  }
  #pragma unroll
  for (int i = 0; i < 2; ++i)
    #pragma unroll
    for (int r = 0; r < 4; ++r)
      mreg[i][r] = masks[(size_t)0 * N_B + n0 + wn * 32 + i * 16 + l4 * 4 + r];
  stageW(0, 0); stageW(1, 1); stageW(2, 2);
  stageXP(0);

  for (int t = 0; t < T_STEPS; ++t) {
    const unsigned short* hread = hbuf + (size_t)(t & 1) * NH;
    unsigned short* hwrite = hbuf + (size_t)((t & 1) ^ 1) * NH;

    // ---- post-barrier critical path: ONLY the 12 h loads ----
    stageH(hread, 0, 0); stageH(hread, 1, 1); stageH(hread, 2, 2);

    f4v acc[2][3];
    #pragma unroll
    for (int i = 0; i < 2; ++i)
      #pragma unroll
      for (int g3 = 0; g3 < 3; ++g3) acc[i][g3] = zero4;

    // ---- kt pipeline: exact counted vmcnt + raw s_barrier ----
#define KT_BODY(KT, VM, DO_STAGE)                                              \
    {                                                                          \
      asm volatile("s_waitcnt vmcnt(" #VM ")" ::: "memory");                   \
      __builtin_amdgcn_s_barrier();                                            \
      __builtin_amdgcn_sched_barrier(0);                                       \
      if (DO_STAGE) { stageH(hread, (KT + 2) % 3, KT + 2); stageW((KT + 2) % 3, KT + 2); } \
      const char* hb = (const char*)&Hs[KT % 3][0];                            \
      const char* wb = (const char*)&Ws[KT % 3][0];                            \
      _Pragma("unroll")                                                        \
      for (int ks = 0; ks < 4; ++ks) {                                         \
        const int kbb = (ks * 64 + l4 * 16) ^ swz_rd;                          \
        s8v a[2], b[3];                                                        \
        _Pragma("unroll")                                                      \
        for (int i = 0; i < 2; ++i) {                                          \
          a[i] = *(const s8v*)(hb + (wn * 32 + i * 16 + l15) * 256 + kbb);     \
          if (zo[i]) a[i] = zer8;                                              \
        }                                                                      \
        _Pragma("unroll")                                                      \
        for (int g3 = 0; g3 < 3; ++g3)                                         \
          b[g3] = *(const s8v*)(wb + (g3 * 32 + wj * 16 + l15) * 256 + kbb);   \
        _Pragma("unroll")                                                      \
        for (int i = 0; i < 2; ++i)                                            \
          _Pragma("unroll")                                                    \
          for (int g3 = 0; g3 < 3; ++g3)                                       \
            acc[i][g3] = __builtin_amdgcn_mfma_f32_16x16x32_bf16(a[i], b[g3],  \
                                                                acc[i][g3], 0, 0, 0); \
      }                                                                        \
    }

    KT_BODY(0, 8,  false)
    KT_BODY(1, 4,  true)
    KT_BODY(2, 10, true)
    KT_BODY(3, 10, true)
    KT_BODY(4, 10, true)
    KT_BODY(5, 10, true)
    KT_BODY(6, 10, false)
    KT_BODY(7, 0,  false)
#undef KT_BODY

    // ---- gates: xp from LDS (kt7's vmcnt(0) drained it), h_prev from registers ----
    #pragma unroll
    for (int i = 0; i < 2; ++i) {
      #pragma unroll
      for (int r = 0; r < 4; ++r) {
        const int n = n0 + wn * 32 + i * 16 + l4 * 4 + r;
        const int nl = wn * 32 + i * 16 + l4 * 4 + r;           // n-local 0..63
        const int jl = wj * 16 + l15;                           // j-local 0..31
        float hprev = hreg[i][r];
        if (rst && mreg[i][r] == 0.0f) hprev = 0.0f;
        const float hr = acc[i][0][r] + br;
        const float hz = acc[i][1][r] + bz;
        const float hn = acc[i][2][r] + bn;
        const char* xb = (const char*)&xpl[0][0][0];
        const int nb = (nl * 2) ^ ((jl & 7) << 4);              // swizzled byte in 128B col
        const float xr = bf2f(*(const unsigned short*)(xb + 0 * 4096 + jl * 128 + nb));
        const float xz = bf2f(*(const unsigned short*)(xb + 1 * 4096 + jl * 128 + nb));
        const float xn = bf2f(*(const unsigned short*)(xb + 2 * 4096 + jl * 128 + nb));
        const float rg = sigmoidf_(xr + hr);
        const float zg = sigmoidf_(xz + hz);
        const float ng = tanhf_(xn + rg * hn);
        const float hnew = (1.f - zg) * ng + zg * hprev;
        hreg[i][r] = hnew;
        const size_t gidx = (size_t)n * H_DIM + jj;
        y[(size_t)t * NH + gidx] = hnew;
        store_bf16_coh(hwrite + gidx, f2bf(hnew));   // through to coherence point
        if (t == T_STEPS - 1) hlast[gidx] = hnew;
      }
    }

    // ---- sync #1: drains vmcnt(0) -> h stores visible; all waves past LDS reads ----
    __syncthreads();

    // ---- h-independent prestage for t+1 overlaps the barrier wait ----
    int rstN = 0;
    bool zoN[2] = {false, false};
    float mregN[2][4];
    if (t + 1 < T_STEPS) {
      rstN = reset[t + 1];
      #pragma unroll
      for (int i = 0; i < 2; ++i) {
        float mv = masks[(size_t)(t + 1) * N_B + n0 + wn * 32 + i * 16 + l15];
        zoN[i] = rstN && (mv == 0.0f);
      }
      #pragma unroll
      for (int i = 0; i < 2; ++i)
        #pragma unroll
        for (int r = 0; r < 4; ++r)
          mregN[i][r] = masks[(size_t)(t + 1) * N_B + n0 + wn * 32 + i * 16 + l4 * 4 + r];
      stageW(0, 0); stageW(1, 1); stageW(2, 2);
      stageXP(t + 1);
    }

    // ---- nt-group barrier (32 blocks, cross-XCD), padded counter, relaxed atomics ----
    if (tid == 0) {
      __hip_atomic_fetch_add(&bar[nt * BAR_STRIDE], 1u, __ATOMIC_RELAXED, __HIP_MEMORY_SCOPE_AGENT);
      const unsigned tgt = 32u * (unsigned)(t + 1);
      while (__hip_atomic_load(&bar[nt * BAR_STRIDE], __ATOMIC_RELAXED, __HIP_MEMORY_SCOPE_AGENT) < tgt)
        __builtin_amdgcn_s_sleep(1);
    }
    __builtin_amdgcn_s_barrier();               // raw: no vmcnt drain (prestage stays in flight)
    __builtin_amdgcn_sched_barrier(0);

    rst = rstN;
    #pragma unroll
    for (int i = 0; i < 2; ++i) {
      zo[i] = zoN[i];
      #pragma unroll
      for (int r = 0; r < 4; ++r) mreg[i][r] = mregN[i][r];
    }
  }
}

// ---------------- final LayerNorm over y rows (in place) ----------------
__global__ __launch_bounds__(256) void ln_kernel(float* __restrict__ y,
                                                 const float* __restrict__ gamma,
                                                 const float* __restrict__ beta) {
  const size_t row = blockIdx.x;
  float* p = y + row * (size_t)H_DIM;
  const int tid = threadIdx.x;
  f4v v = *(const f4v*)(p + tid * 4);
  float s = v[0] + v[1] + v[2] + v[3];
  float q = v[0] * v[0] + v[1] * v[1] + v[2] * v[2] + v[3] * v[3];
  #pragma unroll
  for (int off = 32; off > 0; off >>= 1) {
    s += __shfl_down(s, off);
    q += __shfl_down(q, off);
  }
  __shared__ float sb[8];
  const int wid = tid >> 6, lid = tid & 63;
  if (lid == 0) { sb[wid] = s; sb[4 + wid] = q; }
  __syncthreads();
  float S = sb[0] + sb[1] + sb[2] + sb[3];
  float Q = sb[4] + sb[5] + sb[6] + sb[7];
  float mean = S * (1.f / H_DIM);
  float var = Q * (1.f / H_DIM) - mean * mean;
  float inv = rsqrtf(var + 1e-5f);
  f4v g4 = *(const f4v*)(gamma + tid * 4);
  f4v b4 = *(const f4v*)(beta + tid * 4);
  f4v o;
  #pragma unroll
  for (int e = 0; e < 4; ++e) o[e] = (v[e] - mean) * inv * g4[e] + b4[e];
  *(f4v*)(p + tid * 4) = o;
}

// ---------------- host ----------------
extern "C" void kernel_launch(void* const* d_in, const int* in_sizes, int n_in,
                              void* d_out, int out_size, void* d_ws, size_t ws_size,
                              hipStream_t stream) {
  const float* x     = (const float*)d_in[0];
  const float* hxs   = (const float*)d_in[1];
  const float* masks = (const float*)d_in[2];
  const float* W_ih  = (const float*)d_in[3];
  const float* W_hh  = (const float*)d_in[4];
  const float* b_ih  = (const float*)d_in[5];
  const float* b_hh  = (const float*)d_in[6];
  const float* gamma = (const float*)d_in[7];
  const float* beta  = (const float*)d_in[8];
  float* y = (float*)d_out;                                 // [65536][1024]
  float* hlast = y + (size_t)T_STEPS * N_B * H_DIM;         // [512][1024]

  char* ws = (char*)d_ws;
  unsigned short* Wih_bf = (unsigned short*)ws;  ws += (size_t)G_DIM * D_IN * 2;       // 6.3 MB
  unsigned short* Whh_bf = (unsigned short*)ws;  ws += (size_t)G_DIM * H_DIM * 2;      // 6.3 MB
  unsigned short* xc_bf  = (unsigned short*)ws;  ws += (size_t)M_ALL * D_IN * 2;       // 134 MB
  unsigned short* xpT_bf = (unsigned short*)ws;  ws += (size_t)G_DIM * M_ALL * 2;      // 403 MB
  unsigned short* hbuf   = (unsigned short*)ws;  ws += (size_t)2 * N_B * H_DIM * 2;    // 2.1 MB
  unsigned* bars         = (unsigned*)ws;        ws += 8 * BAR_STRIDE * sizeof(unsigned);
  int* reset             = (int*)ws;             ws += 512;

  hipMemsetAsync(bars, 0, 8 * BAR_STRIDE * sizeof(unsigned), stream);
  cvt_bf16<<<1024, 256, 0, stream>>>(W_ih, Wih_bf, (long)G_DIM * D_IN / 4);
  cvt_bf16<<<1024, 256, 0, stream>>>(W_hh, Whh_bf, (long)G_DIM * H_DIM / 4);
  cvt_bf16<<<512, 256, 0, stream>>>(hxs, hbuf, (long)N_B * H_DIM / 4);   // hbuf[0] = bf16(h0)
  reset_kernel<<<128, 512, 0, stream>>>(masks, reset);
  cvt_bf16<<<4096, 256, 0, stream>>>(x, xc_bf, (long)M_ALL * D_IN / 4);

  dim3 gg(G_DIM / 128, M_ALL / 128);   // (24, 512) — one GEMM for all timesteps
  gemm_xp<<<gg, 256, 0, stream>>>(xc_bf, Wih_bf, b_ih, xpT_bf);

  rnn_all<<<256, 256, 0, stream>>>(Whh_bf, xpT_bf, masks, reset, b_hh,
                                   hxs, hbuf, y, hlast, bars);

  ln_kernel<<<T_STEPS * N_B, 256, 0, stream>>>(y, gamma, beta);
}